// Round 9
// baseline (341.071 us; speedup 1.0000x reference)
//
#include <hip/hip_runtime.h>
#include <hip/hip_bf16.h>

using bf16 = __hip_bfloat16;
typedef __attribute__((ext_vector_type(8))) short short8;
typedef __attribute__((ext_vector_type(4))) float f32x4;

constexpr int N   = 50000;
constexpr int E   = 800000;
constexpr int NIN = 300;
constexpr int H   = 4;
constexpr int C   = 64;
constexpr int HC  = H * C;      // 256
constexpr int G   = 256;
constexpr int NOUT = 768;
constexpr int NKB = 10;         // K blocks of 32 (K padded 300->320)
constexpr int NT  = 782;        // row tiles of 64 (50048 rows)
constexpr int DCAP = 64;        // fixed CSR bucket capacity (P(deg>=64) ~ 1e-21 at Poisson(16))
constexpr int EPB  = 782;       // edges per k_lin4 block (1024 * 782 >= E)

__device__ __forceinline__ float b2f(bf16 v) { return __bfloat162float(v); }
__device__ __forceinline__ float us2f(unsigned short u) {
    bf16 b; *(unsigned short*)&b = u; return __bfloat162float(b);
}
__device__ __forceinline__ unsigned short f2us(float f) {
    bf16 b = __float2bfloat16(f); return *(unsigned short*)&b;
}
__device__ __forceinline__ float lrelu_att(float v) { return v > 0.f ? v : 0.2f * v; }
__device__ __forceinline__ float lrelu_act(float v) { return v > 0.f ? v : 0.01f * v; }
__device__ __forceinline__ float ldin(const void* p, int isbf, size_t i) {
    return isbf ? b2f(((const bf16*)p)[i]) : ((const float*)p)[i];
}
__device__ __forceinline__ short8 pack8u(ushort4 lo, ushort4 hi) {
    short8 r;
    r[0] = (short)lo.x; r[1] = (short)lo.y; r[2] = (short)lo.z; r[3] = (short)lo.w;
    r[4] = (short)hi.x; r[5] = (short)hi.y; r[6] = (short)hi.z; r[7] = (short)hi.w;
    return r;
}
__device__ __forceinline__ short8 pack8f(float4 lo, float4 hi) {
    short8 r;
    r[0] = (short)f2us(lo.x); r[1] = (short)f2us(lo.y); r[2] = (short)f2us(lo.z); r[3] = (short)f2us(lo.w);
    r[4] = (short)f2us(hi.x); r[5] = (short)f2us(hi.y); r[6] = (short)f2us(hi.z); r[7] = (short)f2us(hi.w);
    return r;
}

// A-fragment loaders: kb is a compile-time constant under full unroll, so the
// branches fold away. kb==9 is the K tail (300 of 320).
__device__ __forceinline__ short8 loadA_bf(const unsigned short* __restrict__ xr, int kb, int q) {
    ushort4 z = make_ushort4(0, 0, 0, 0);
    ushort4 lo = z, hi = z;
    if (kb < 9) {
        lo = *(const ushort4*)(xr + kb * 32);
        hi = *(const ushort4*)(xr + kb * 32 + 4);
    } else if (q == 0) {
        lo = *(const ushort4*)(xr + 288); hi = *(const ushort4*)(xr + 292);
    } else if (q == 1) {
        lo = *(const ushort4*)(xr + 288);
    }
    return pack8u(lo, hi);
}
__device__ __forceinline__ short8 loadA_f32(const float* __restrict__ xf, int kb, int q) {
    float4 zf = make_float4(0.f, 0.f, 0.f, 0.f);
    float4 lo = zf, hi = zf;
    if (kb < 9) {
        lo = *(const float4*)(xf + kb * 32);
        hi = *(const float4*)(xf + kb * 32 + 4);
    } else if (q == 0) {
        lo = *(const float4*)(xf + 288); hi = *(const float4*)(xf + 292);
    } else if (q == 1) {
        lo = *(const float4*)(xf + 288);
    }
    return pack8f(lo, hi);
}

// in-block dtype detection (reads first 256 uint16s of x; deterministic)
__device__ __forceinline__ int block_detect(const unsigned short* __restrict__ xr) {
    __shared__ int cnt_s;
    if (threadIdx.x == 0) cnt_s = 0;
    __syncthreads();
    unsigned short u = xr[threadIdx.x & 255];
    int ex = (u >> 7) & 0xFF;
    int ok = (ex == 0) || (ex >= 100 && ex <= 140);
    if (threadIdx.x < 256) atomicAdd(&cnt_s, ok);
    __syncthreads();
    return (cnt_s >= 240) ? 1 : 0;   // 1 = bf16 inputs
}

// ---------------- pre: zero cnt | detect | swizzle w | graph ranges ----------------
constexpr int NZ  = N;                     // ints to zero (cnt only; sums eliminated)
constexpr int NZB = (NZ + 255) / 256;      // 196
__global__ __launch_bounds__(256) void k_pre(const unsigned short* __restrict__ xr,
                                             const void* __restrict__ w,
                                             const int* __restrict__ batch,
                                             int* __restrict__ flag,
                                             int* __restrict__ zp,
                                             unsigned short* __restrict__ bswz,
                                             int* __restrict__ gs) {
    int b = blockIdx.x;
    if (b < NZB) {
        int i = b * 256 + threadIdx.x;
        if (i < NZ) zp[i] = 0;
        if (b == 0) {
            int isbf = block_detect(xr);
            if (threadIdx.x == 0) *flag = isbf;
        }
    } else if (b < NZB + 40) {
        int isbf = block_detect(xr);
        int fb = (b - NZB) * 4 + (threadIdx.x >> 6);   // kb*16+nb, 0..159
        if (fb < 160) {
            int kb = fb >> 4, nb = fb & 15;
            int lane = threadIdx.x & 63;
            int q = lane >> 4, cl = lane & 15;
            int n = nb * 16 + cl;
            unsigned short v[8];
#pragma unroll
            for (int j = 0; j < 8; j++) {
                int k = kb * 32 + q * 8 + j;
                float f = (k < NIN) ? ldin(w, isbf, (size_t)k * HC + n) : 0.f;
                v[j] = f2us(f);
            }
            ushort4* dst = (ushort4*)(bswz + ((size_t)fb * 64 + lane) * 8);
            dst[0] = make_ushort4(v[0], v[1], v[2], v[3]);
            dst[1] = make_ushort4(v[4], v[5], v[6], v[7]);
        }
    } else {
        int g = threadIdx.x;   // graph start offsets, batch sorted
        int lo = 0, hi = N;
        while (lo < hi) {
            int mid = (lo + hi) >> 1;
            if (batch[mid] < g) lo = mid + 1;
            else hi = mid;
        }
        gs[g] = lo;
        if (g == 0) gs[G] = N;
    }
}

// ---------------- h = x @ lin_w via MFMA + overlapped CSR build ----------------
// 40 KB LDS/block -> 4 blocks/CU, 16 waves/CU; depth-2 A register pipeline (no spill).
// XCD-coherent decode: all 4 quarters of a tile-slot share bid%8 (= same XCD).
// NEW: the single-pass bucketed CSR build (was k_build, ~20 us standalone + launch
// gap) runs in the prologue, overlapped with LDS staging / barrier wait. Stream
// order guarantees cnt is zeroed (k_pre) before this and complete before k_agg.
__global__ __launch_bounds__(256, 4) void k_lin4(const void* __restrict__ x,
                                                 const unsigned short* __restrict__ bswz,
                                                 const void* __restrict__ att_s,
                                                 const void* __restrict__ att_d,
                                                 unsigned short* __restrict__ hb,
                                                 float* __restrict__ a_src,
                                                 float* __restrict__ a_dst,
                                                 const int* __restrict__ flag,
                                                 const int* __restrict__ ei,
                                                 int* __restrict__ cnt,
                                                 int* __restrict__ csrB) {
    __shared__ unsigned short bs[40 * 64 * 8];   // 40 KB: 10 kb x 4 nb fragments
    int isbf = *flag;
    int t = threadIdx.x;
    // bid -> (XCD c, quarter, slot): all 4 quarters of a slot have the same c.
    int c       = blockIdx.x & 7;
    int j       = blockIdx.x >> 3;       // 0..127
    int quarter = j & 3;                 // 0..3 (one head each)
    int bslot   = (j >> 2) * 8 + c;      // 0..255, tail slots spread across XCDs
    // ---- stage this quarter of B into LDS (2560 int4, 10 per thread) ----
    for (int i = t; i < 40 * 64; i += 256) {
        int f = i >> 6, lane = i & 63;
        int kb = f >> 2, nbl = f & 3;
        const int4* src = (const int4*)(bswz + ((size_t)(kb * 16 + quarter * 4 + nbl) * 64 + lane) * 8);
        ((int4*)bs)[i] = *src;
    }
    // ---- overlapped edge scatter: this block's slice of E ----
    for (int i = t; i < EPB; i += 256) {
        int e = blockIdx.x * EPB + i;
        if (e < E) {
            int s = ei[e], d = ei[E + e];
            int pos = atomicAdd(&cnt[d], 1);
            if (pos < DCAP) csrB[(size_t)d * DCAP + pos] = s;
        }
    }
    __syncthreads();

    int wave = t >> 6, lane = t & 63;
    int q = lane >> 4, cl = lane & 15;
    int hh = quarter;
    // tile-invariant attention vectors (hoisted out of the tile loop)
    float as_h[4], ad_h[4];
#pragma unroll
    for (int nbl = 0; nbl < 4; nbl++) {
        as_h[nbl] = ldin(att_s, isbf, (quarter * 4 + nbl) * 16 + cl);
        ad_h[nbl] = ldin(att_d, isbf, (quarter * 4 + nbl) * 16 + cl);
    }
    for (int tile = bslot; tile < NT; tile += 256) {
        int m0 = tile * 64 + wave * 16;
        int row = m0 + cl; if (row >= N) row = N - 1;
        f32x4 acc[4];
#pragma unroll
        for (int nbl = 0; nbl < 4; nbl++) acc[nbl] = f32x4{0.f, 0.f, 0.f, 0.f};
        if (isbf) {
            const unsigned short* xr = (const unsigned short*)x + (size_t)row * NIN + q * 8;
            short8 a_cur = loadA_bf(xr, 0, q);
            short8 a_nxt = loadA_bf(xr, 1, q);
#pragma unroll
            for (int kb = 0; kb < NKB; kb++) {
                short8 a_pf = {};
                if (kb + 2 < NKB) a_pf = loadA_bf(xr, kb + 2, q);
                short8 bfr[4];
#pragma unroll
                for (int nbl = 0; nbl < 4; nbl++)
                    bfr[nbl] = *(const short8*)(bs + ((size_t)(kb * 4 + nbl) * 64 + lane) * 8);
#pragma unroll
                for (int nbl = 0; nbl < 4; nbl++)
                    acc[nbl] = __builtin_amdgcn_mfma_f32_16x16x32_bf16(a_cur, bfr[nbl], acc[nbl], 0, 0, 0);
                a_cur = a_nxt; a_nxt = a_pf;
            }
        } else {
            const float* xf = (const float*)x + (size_t)row * NIN + q * 8;
            short8 a_cur = loadA_f32(xf, 0, q);
            short8 a_nxt = loadA_f32(xf, 1, q);
#pragma unroll
            for (int kb = 0; kb < NKB; kb++) {
                short8 a_pf = {};
                if (kb + 2 < NKB) a_pf = loadA_f32(xf, kb + 2, q);
                short8 bfr[4];
#pragma unroll
                for (int nbl = 0; nbl < 4; nbl++)
                    bfr[nbl] = *(const short8*)(bs + ((size_t)(kb * 4 + nbl) * 64 + lane) * 8);
#pragma unroll
                for (int nbl = 0; nbl < 4; nbl++)
                    acc[nbl] = __builtin_amdgcn_mfma_f32_16x16x32_bf16(a_cur, bfr[nbl], acc[nbl], 0, 0, 0);
                a_cur = a_nxt; a_nxt = a_pf;
            }
        }
        // epilogue: store h (bf16, interleaved) + attention partials
        float ps[4], pd[4];
#pragma unroll
        for (int r = 0; r < 4; r++) { ps[r] = 0.f; pd[r] = 0.f; }
#pragma unroll
        for (int nbl = 0; nbl < 4; nbl++) {
            int nb = quarter * 4 + nbl;
#pragma unroll
            for (int r = 0; r < 4; r++) {
                float v = acc[nbl][r];
                ps[r] += v * as_h[nbl];
                pd[r] += v * ad_h[nbl];
                int gm = m0 + q * 4 + r;
                if (gm < N) hb[(size_t)gm * HC + nb * 16 + cl] = f2us(v);
            }
        }
#pragma unroll
        for (int r = 0; r < 4; r++) {
            float vs = ps[r], vd = pd[r];
#pragma unroll
            for (int m = 1; m < 16; m <<= 1) {
                vs += __shfl_xor(vs, m, 64);
                vd += __shfl_xor(vd, m, 64);
            }
            int gm = m0 + q * 4 + r;
            if (cl == 0 && gm < N) {
                a_src[gm * 4 + hh] = vs;
                a_dst[gm * 4 + hh] = vd;
            }
        }
    }
}

// ---------------- per-node aggregation (round-4 exact form, 66 us measured) ----------------
// Wave per node, lane = head*16 + ch16, depth-2 rotate pipeline on bucketed CSR.
__global__ __launch_bounds__(256) void k_agg(const unsigned short* __restrict__ hb,
                                             const float* __restrict__ a_src,
                                             const float* __restrict__ a_dst,
                                             const int* __restrict__ cnt,
                                             const int* __restrict__ csrB,
                                             const void* __restrict__ bias,
                                             unsigned short* __restrict__ outn,
                                             const int* __restrict__ flag) {
    int isbf = *flag;
    int wave = threadIdx.x >> 6, lane = threadIdx.x & 63;
    int n = blockIdx.x * 4 + wave;
    if (n >= N) return;
    int head = lane >> 4;
    float adn = a_dst[n * 4 + head];
    float wself = __expf(lrelu_att(a_src[n * 4 + head] + adn));
    ushort4 hv = *(const ushort4*)&hb[(size_t)n * HC + lane * 4];
    float4 acc;
    acc.x = us2f(hv.x) * wself;
    acc.y = us2f(hv.y) * wself;
    acc.z = us2f(hv.z) * wself;
    acc.w = us2f(hv.w) * wself;
    float ssum = wself;
    int dg = cnt[n]; if (dg > DCAP) dg = DCAP;
    const int* lst = csrB + (size_t)n * DCAP;
    int p0 = 0, p1 = dg;
    int p = p0;
    // pipeline state: group A = data in flight / being consumed; ib* = next group's indices
    ushort4 ga0, ga1, ga2, ga3;
    float wa0, wa1, wa2, wa3;
    int ib0 = 0, ib1 = 0, ib2 = 0, ib3 = 0;
    if (p + 4 <= p1) {
        int i0 = lst[p], i1 = lst[p + 1], i2 = lst[p + 2], i3 = lst[p + 3];
        ga0 = *(const ushort4*)&hb[(size_t)i0 * HC + lane * 4];
        ga1 = *(const ushort4*)&hb[(size_t)i1 * HC + lane * 4];
        ga2 = *(const ushort4*)&hb[(size_t)i2 * HC + lane * 4];
        ga3 = *(const ushort4*)&hb[(size_t)i3 * HC + lane * 4];
        wa0 = a_src[(size_t)i0 * 4 + head];
        wa1 = a_src[(size_t)i1 * 4 + head];
        wa2 = a_src[(size_t)i2 * 4 + head];
        wa3 = a_src[(size_t)i3 * 4 + head];
    }
    if (p + 8 <= p1) {
        ib0 = lst[p + 4]; ib1 = lst[p + 5]; ib2 = lst[p + 6]; ib3 = lst[p + 7];
    }
    while (p + 8 <= p1) {
        // issue group-B gathers immediately (indices already resident)
        ushort4 gb0 = *(const ushort4*)&hb[(size_t)ib0 * HC + lane * 4];
        ushort4 gb1 = *(const ushort4*)&hb[(size_t)ib1 * HC + lane * 4];
        ushort4 gb2 = *(const ushort4*)&hb[(size_t)ib2 * HC + lane * 4];
        ushort4 gb3 = *(const ushort4*)&hb[(size_t)ib3 * HC + lane * 4];
        float wb0 = a_src[(size_t)ib0 * 4 + head];
        float wb1 = a_src[(size_t)ib1 * 4 + head];
        float wb2 = a_src[(size_t)ib2 * 4 + head];
        float wb3 = a_src[(size_t)ib3 * 4 + head];
        // prefetch indices two groups ahead
        int ic0 = ib0, ic1 = ib1, ic2 = ib2, ic3 = ib3;
        if (p + 12 <= p1) {
            ic0 = lst[p + 8]; ic1 = lst[p + 9]; ic2 = lst[p + 10]; ic3 = lst[p + 11];
        }
        // consume group A (its loads have had a full iteration of latency cover)
        float e0 = __expf(lrelu_att(wa0 + adn));
        float e1 = __expf(lrelu_att(wa1 + adn));
        float e2 = __expf(lrelu_att(wa2 + adn));
        float e3 = __expf(lrelu_att(wa3 + adn));
        acc.x += us2f(ga0.x) * e0 + us2f(ga1.x) * e1 + us2f(ga2.x) * e2 + us2f(ga3.x) * e3;
        acc.y += us2f(ga0.y) * e0 + us2f(ga1.y) * e1 + us2f(ga2.y) * e2 + us2f(ga3.y) * e3;
        acc.z += us2f(ga0.z) * e0 + us2f(ga1.z) * e1 + us2f(ga2.z) * e2 + us2f(ga3.z) * e3;
        acc.w += us2f(ga0.w) * e0 + us2f(ga1.w) * e1 + us2f(ga2.w) * e2 + us2f(ga3.w) * e3;
        ssum += (e0 + e1) + (e2 + e3);
        // rotate B -> A
        ga0 = gb0; ga1 = gb1; ga2 = gb2; ga3 = gb3;
        wa0 = wb0; wa1 = wb1; wa2 = wb2; wa3 = wb3;
        ib0 = ic0; ib1 = ic1; ib2 = ic2; ib3 = ic3;
        p += 4;
    }
    if (p + 4 <= p1) {
        float e0 = __expf(lrelu_att(wa0 + adn));
        float e1 = __expf(lrelu_att(wa1 + adn));
        float e2 = __expf(lrelu_att(wa2 + adn));
        float e3 = __expf(lrelu_att(wa3 + adn));
        acc.x += us2f(ga0.x) * e0 + us2f(ga1.x) * e1 + us2f(ga2.x) * e2 + us2f(ga3.x) * e3;
        acc.y += us2f(ga0.y) * e0 + us2f(ga1.y) * e1 + us2f(ga2.y) * e2 + us2f(ga3.y) * e3;
        acc.z += us2f(ga0.z) * e0 + us2f(ga1.z) * e1 + us2f(ga2.z) * e2 + us2f(ga3.z) * e3;
        acc.w += us2f(ga0.w) * e0 + us2f(ga1.w) * e1 + us2f(ga2.w) * e2 + us2f(ga3.w) * e3;
        ssum += (e0 + e1) + (e2 + e3);
        p += 4;
    }
    for (; p < p1; p++) {
        int s = lst[p];
        float wv = __expf(lrelu_att(a_src[(size_t)s * 4 + head] + adn));
        ushort4 hs = *(const ushort4*)&hb[(size_t)s * HC + lane * 4];
        acc.x += us2f(hs.x) * wv;
        acc.y += us2f(hs.y) * wv;
        acc.z += us2f(hs.z) * wv;
        acc.w += us2f(hs.w) * wv;
        ssum += wv;
    }
    float inv = 1.f / ssum;
    ushort4 o;
    o.x = f2us(lrelu_act(acc.x * inv + ldin(bias, isbf, lane * 4 + 0)));
    o.y = f2us(lrelu_act(acc.y * inv + ldin(bias, isbf, lane * 4 + 1)));
    o.z = f2us(lrelu_act(acc.z * inv + ldin(bias, isbf, lane * 4 + 2)));
    o.w = f2us(lrelu_act(acc.w * inv + ldin(bias, isbf, lane * 4 + 3)));
    *(ushort4*)&outn[(size_t)n * HC + lane * 4] = o;
}

// ---------------- fused pool + FC: one block per graph ----------------
// Replaces k_pool2 + k_fc (2 launches + sums round-trip -> 1 launch, no sums).
// Phase 1: thread t pools channel t over the graph's rows (coalesced 512 B/row)
// into LDS with the mean fold. Phase 2: each thread computes 3 of 768 outputs;
// pl[k] is an LDS broadcast (conflict-free), fw reads coalesced across t.
__global__ __launch_bounds__(256) void k_fcp(const unsigned short* __restrict__ outn,
                                             const int* __restrict__ gs,
                                             const void* __restrict__ fw,
                                             const void* __restrict__ fb,
                                             void* __restrict__ out,
                                             const int* __restrict__ flag) {
    __shared__ float pl[HC];
    int isbf = *flag;
    int g = blockIdx.x, t = threadIdx.x;
    int s = gs[g], e2 = gs[g + 1];
    float a0 = 0.f, a1 = 0.f, a2 = 0.f, a3 = 0.f;
    int r = s;
    for (; r + 4 <= e2; r += 4) {
        a0 += us2f(outn[(size_t)(r + 0) * HC + t]);
        a1 += us2f(outn[(size_t)(r + 1) * HC + t]);
        a2 += us2f(outn[(size_t)(r + 2) * HC + t]);
        a3 += us2f(outn[(size_t)(r + 3) * HC + t]);
    }
    for (; r < e2; r++) a0 += us2f(outn[(size_t)r * HC + t]);
    int c = e2 - s;
    float inv = 1.f / (float)(c > 1 ? c : 1);
    pl[t] = ((a0 + a1) + (a2 + a3)) * inv;
    __syncthreads();
#pragma unroll
    for (int oo = 0; oo < NOUT / 256; oo++) {
        int o = oo * 256 + t;
        float acc = ldin(fb, isbf, o);
#pragma unroll 8
        for (int k = 0; k < HC; k++) acc += pl[k] * ldin(fw, isbf, (size_t)k * NOUT + o);
        size_t oi = (size_t)g * NOUT + o;
        if (isbf) ((bf16*)out)[oi] = __float2bfloat16(acc);
        else      ((float*)out)[oi] = acc;
    }
}

extern "C" void kernel_launch(void* const* d_in, const int* in_sizes, int n_in,
                              void* d_out, int out_size, void* d_ws, size_t ws_size,
                              hipStream_t stream) {
    const void* x     = d_in[0];
    const int*  ei    = (const int*)d_in[1];
    const int*  batch = (const int*)d_in[2];
    const void* lin_w = d_in[3];
    const void* att_s = d_in[4];
    const void* att_d = d_in[5];
    const void* bias  = d_in[6];
    const void* fc1w  = d_in[7];
    const void* fc1b  = d_in[8];

    char* p = (char*)d_ws;
    unsigned short* hb   = (unsigned short*)p; p += (size_t)N * HC * 2;   // 25.6 MB
    unsigned short* outn = (unsigned short*)p; p += (size_t)N * HC * 2;   // 25.6 MB
    float* a_src  = (float*)p; p += (size_t)N * H * 4;
    float* a_dst  = (float*)p; p += (size_t)N * H * 4;
    int* cnt      = (int*)p;   p += (size_t)N * 4;
    int* csrB     = (int*)p;   p += (size_t)N * DCAP * 4;                 // 12.8 MB bucketed CSR
    unsigned short* bswz = (unsigned short*)p; p += (size_t)160 * 64 * 8 * 2;
    int* gs       = (int*)p;   p += (size_t)(G + 4) * 4;
    int* flag     = (int*)p;   p += 16;

    k_pre<<<NZB + 40 + 1, 256, 0, stream>>>((const unsigned short*)x, lin_w, batch,
                                            flag, cnt, bswz, gs);
    k_lin4<<<1024, 256, 0, stream>>>(x, bswz, att_s, att_d, hb, a_src, a_dst, flag,
                                     ei, cnt, csrB);
    k_agg<<<(N + 3) / 4, 256, 0, stream>>>(hb, a_src, a_dst, cnt, csrB, bias, outn, flag);
    k_fcp<<<G, 256, 0, stream>>>(outn, gs, fc1w, fc1b, d_out, flag);
}

// Round 10
// 274.103 us; speedup vs baseline: 1.2443x; 1.2443x over previous
//
#include <hip/hip_runtime.h>
#include <hip/hip_bf16.h>

using bf16 = __hip_bfloat16;
typedef __attribute__((ext_vector_type(8))) short short8;
typedef __attribute__((ext_vector_type(4))) float f32x4;

constexpr int N   = 50000;
constexpr int E   = 800000;
constexpr int NIN = 300;
constexpr int H   = 4;
constexpr int C   = 64;
constexpr int HC  = H * C;      // 256
constexpr int G   = 256;
constexpr int NOUT = 768;
constexpr int NKB = 10;         // K blocks of 32 (K padded 300->320)
constexpr int NT  = 782;        // row tiles of 64 (50048 rows)
constexpr int DCAP = 64;        // fixed CSR bucket capacity (P(deg>=64) ~ 1e-21 at Poisson(16))
constexpr int SCB  = (E + 255) / 256;   // 3125 scatter blocks appended to k_pre

__device__ __forceinline__ float b2f(bf16 v) { return __bfloat162float(v); }
__device__ __forceinline__ float us2f(unsigned short u) {
    bf16 b; *(unsigned short*)&b = u; return __bfloat162float(b);
}
__device__ __forceinline__ unsigned short f2us(float f) {
    bf16 b = __float2bfloat16(f); return *(unsigned short*)&b;
}
__device__ __forceinline__ float lrelu_att(float v) { return v > 0.f ? v : 0.2f * v; }
__device__ __forceinline__ float lrelu_act(float v) { return v > 0.f ? v : 0.01f * v; }
__device__ __forceinline__ float ldin(const void* p, int isbf, size_t i) {
    return isbf ? b2f(((const bf16*)p)[i]) : ((const float*)p)[i];
}
__device__ __forceinline__ short8 pack8u(ushort4 lo, ushort4 hi) {
    short8 r;
    r[0] = (short)lo.x; r[1] = (short)lo.y; r[2] = (short)lo.z; r[3] = (short)lo.w;
    r[4] = (short)hi.x; r[5] = (short)hi.y; r[6] = (short)hi.z; r[7] = (short)hi.w;
    return r;
}
__device__ __forceinline__ short8 pack8f(float4 lo, float4 hi) {
    short8 r;
    r[0] = (short)f2us(lo.x); r[1] = (short)f2us(lo.y); r[2] = (short)f2us(lo.z); r[3] = (short)f2us(lo.w);
    r[4] = (short)f2us(hi.x); r[5] = (short)f2us(hi.y); r[6] = (short)f2us(hi.z); r[7] = (short)f2us(hi.w);
    return r;
}

// A-fragment loaders: kb is a compile-time constant under full unroll, so the
// branches fold away. kb==9 is the K tail (300 of 320).
__device__ __forceinline__ short8 loadA_bf(const unsigned short* __restrict__ xr, int kb, int q) {
    ushort4 z = make_ushort4(0, 0, 0, 0);
    ushort4 lo = z, hi = z;
    if (kb < 9) {
        lo = *(const ushort4*)(xr + kb * 32);
        hi = *(const ushort4*)(xr + kb * 32 + 4);
    } else if (q == 0) {
        lo = *(const ushort4*)(xr + 288); hi = *(const ushort4*)(xr + 292);
    } else if (q == 1) {
        lo = *(const ushort4*)(xr + 288);
    }
    return pack8u(lo, hi);
}
__device__ __forceinline__ short8 loadA_f32(const float* __restrict__ xf, int kb, int q) {
    float4 zf = make_float4(0.f, 0.f, 0.f, 0.f);
    float4 lo = zf, hi = zf;
    if (kb < 9) {
        lo = *(const float4*)(xf + kb * 32);
        hi = *(const float4*)(xf + kb * 32 + 4);
    } else if (q == 0) {
        lo = *(const float4*)(xf + 288); hi = *(const float4*)(xf + 292);
    } else if (q == 1) {
        lo = *(const float4*)(xf + 288);
    }
    return pack8f(lo, hi);
}

// in-block dtype detection (reads first 256 uint16s of x; deterministic)
__device__ __forceinline__ int block_detect(const unsigned short* __restrict__ xr) {
    __shared__ int cnt_s;
    if (threadIdx.x == 0) cnt_s = 0;
    __syncthreads();
    unsigned short u = xr[threadIdx.x & 255];
    int ex = (u >> 7) & 0xFF;
    int ok = (ex == 0) || (ex >= 100 && ex <= 140);
    if (threadIdx.x < 256) atomicAdd(&cnt_s, ok);
    __syncthreads();
    return (cnt_s >= 240) ? 1 : 0;   // 1 = bf16 inputs
}

// ---------------- pre: detect | swizzle w | graph ranges | CSR scatter ----------------
// cnt is zeroed by hipMemsetAsync BEFORE this kernel (stream-ordered), so the
// scatter blocks (b >= 41) have no intra-kernel ordering dependency. They are
// shape-identical to the standalone k_build that measured ~20 us: 3125 free
// blocks with nothing barrier-blocked behind them (round-9's prologue fusion
// put the scatter in front of k_lin4's barrier -> +55 us; this placement
// overlaps it with the swizzle/gs work instead).
__global__ __launch_bounds__(256) void k_pre(const unsigned short* __restrict__ xr,
                                             const void* __restrict__ w,
                                             const int* __restrict__ batch,
                                             int* __restrict__ flag,
                                             unsigned short* __restrict__ bswz,
                                             int* __restrict__ gs,
                                             const int* __restrict__ ei,
                                             int* __restrict__ cnt,
                                             int* __restrict__ csrB) {
    int b = blockIdx.x;
    if (b < 40) {
        int isbf = block_detect(xr);
        if (b == 0 && threadIdx.x == 0) *flag = isbf;
        int fb = b * 4 + (threadIdx.x >> 6);   // kb*16+nb, 0..159
        if (fb < 160) {
            int kb = fb >> 4, nb = fb & 15;
            int lane = threadIdx.x & 63;
            int q = lane >> 4, cl = lane & 15;
            int n = nb * 16 + cl;
            unsigned short v[8];
#pragma unroll
            for (int j = 0; j < 8; j++) {
                int k = kb * 32 + q * 8 + j;
                float f = (k < NIN) ? ldin(w, isbf, (size_t)k * HC + n) : 0.f;
                v[j] = f2us(f);
            }
            ushort4* dst = (ushort4*)(bswz + ((size_t)fb * 64 + lane) * 8);
            dst[0] = make_ushort4(v[0], v[1], v[2], v[3]);
            dst[1] = make_ushort4(v[4], v[5], v[6], v[7]);
        }
    } else if (b == 40) {
        int g = threadIdx.x;   // graph start offsets, batch sorted
        int lo = 0, hi = N;
        while (lo < hi) {
            int mid = (lo + hi) >> 1;
            if (batch[mid] < g) lo = mid + 1;
            else hi = mid;
        }
        gs[g] = lo;
        if (g == 0) gs[G] = N;
    } else {
        int e = (b - 41) * 256 + threadIdx.x;
        if (e < E) {
            int s = ei[e], d = ei[E + e];
            int pos = atomicAdd(&cnt[d], 1);
            if (pos < DCAP) csrB[(size_t)d * DCAP + pos] = s;
        }
    }
}

// ---------------- h = x @ lin_w via MFMA; B-QUARTER resident in LDS ----------------
// Round-8 exact form (measured <= 66 us). 40 KB LDS/block -> 4 blocks/CU, 16 waves/CU;
// depth-2 A register pipeline (no spill); XCD-coherent quarter decode.
__global__ __launch_bounds__(256, 4) void k_lin4(const void* __restrict__ x,
                                                 const unsigned short* __restrict__ bswz,
                                                 const void* __restrict__ att_s,
                                                 const void* __restrict__ att_d,
                                                 unsigned short* __restrict__ hb,
                                                 float* __restrict__ a_src,
                                                 float* __restrict__ a_dst,
                                                 const int* __restrict__ flag) {
    __shared__ unsigned short bs[40 * 64 * 8];   // 40 KB: 10 kb x 4 nb fragments
    int isbf = *flag;
    int t = threadIdx.x;
    // bid -> (XCD c, quarter, slot): all 4 quarters of a slot have the same c.
    int c       = blockIdx.x & 7;
    int j       = blockIdx.x >> 3;       // 0..127
    int quarter = j & 3;                 // 0..3 (one head each)
    int bslot   = (j >> 2) * 8 + c;      // 0..255, tail slots spread across XCDs
    // ---- stage this quarter of B into LDS once (2560 int4, 10 per thread) ----
    for (int i = t; i < 40 * 64; i += 256) {
        int f = i >> 6, lane = i & 63;
        int kb = f >> 2, nbl = f & 3;
        const int4* src = (const int4*)(bswz + ((size_t)(kb * 16 + quarter * 4 + nbl) * 64 + lane) * 8);
        ((int4*)bs)[i] = *src;
    }
    __syncthreads();

    int wave = t >> 6, lane = t & 63;
    int q = lane >> 4, cl = lane & 15;
    int hh = quarter;
    // tile-invariant attention vectors (hoisted out of the tile loop)
    float as_h[4], ad_h[4];
#pragma unroll
    for (int nbl = 0; nbl < 4; nbl++) {
        as_h[nbl] = ldin(att_s, isbf, (quarter * 4 + nbl) * 16 + cl);
        ad_h[nbl] = ldin(att_d, isbf, (quarter * 4 + nbl) * 16 + cl);
    }
    for (int tile = bslot; tile < NT; tile += 256) {
        int m0 = tile * 64 + wave * 16;
        int row = m0 + cl; if (row >= N) row = N - 1;
        f32x4 acc[4];
#pragma unroll
        for (int nbl = 0; nbl < 4; nbl++) acc[nbl] = f32x4{0.f, 0.f, 0.f, 0.f};
        if (isbf) {
            const unsigned short* xr = (const unsigned short*)x + (size_t)row * NIN + q * 8;
            short8 a_cur = loadA_bf(xr, 0, q);
            short8 a_nxt = loadA_bf(xr, 1, q);
#pragma unroll
            for (int kb = 0; kb < NKB; kb++) {
                short8 a_pf = {};
                if (kb + 2 < NKB) a_pf = loadA_bf(xr, kb + 2, q);
                short8 bfr[4];
#pragma unroll
                for (int nbl = 0; nbl < 4; nbl++)
                    bfr[nbl] = *(const short8*)(bs + ((size_t)(kb * 4 + nbl) * 64 + lane) * 8);
#pragma unroll
                for (int nbl = 0; nbl < 4; nbl++)
                    acc[nbl] = __builtin_amdgcn_mfma_f32_16x16x32_bf16(a_cur, bfr[nbl], acc[nbl], 0, 0, 0);
                a_cur = a_nxt; a_nxt = a_pf;
            }
        } else {
            const float* xf = (const float*)x + (size_t)row * NIN + q * 8;
            short8 a_cur = loadA_f32(xf, 0, q);
            short8 a_nxt = loadA_f32(xf, 1, q);
#pragma unroll
            for (int kb = 0; kb < NKB; kb++) {
                short8 a_pf = {};
                if (kb + 2 < NKB) a_pf = loadA_f32(xf, kb + 2, q);
                short8 bfr[4];
#pragma unroll
                for (int nbl = 0; nbl < 4; nbl++)
                    bfr[nbl] = *(const short8*)(bs + ((size_t)(kb * 4 + nbl) * 64 + lane) * 8);
#pragma unroll
                for (int nbl = 0; nbl < 4; nbl++)
                    acc[nbl] = __builtin_amdgcn_mfma_f32_16x16x32_bf16(a_cur, bfr[nbl], acc[nbl], 0, 0, 0);
                a_cur = a_nxt; a_nxt = a_pf;
            }
        }
        // epilogue: store h (bf16, interleaved) + attention partials
        float ps[4], pd[4];
#pragma unroll
        for (int r = 0; r < 4; r++) { ps[r] = 0.f; pd[r] = 0.f; }
#pragma unroll
        for (int nbl = 0; nbl < 4; nbl++) {
            int nb = quarter * 4 + nbl;
#pragma unroll
            for (int r = 0; r < 4; r++) {
                float v = acc[nbl][r];
                ps[r] += v * as_h[nbl];
                pd[r] += v * ad_h[nbl];
                int gm = m0 + q * 4 + r;
                if (gm < N) hb[(size_t)gm * HC + nb * 16 + cl] = f2us(v);
            }
        }
#pragma unroll
        for (int r = 0; r < 4; r++) {
            float vs = ps[r], vd = pd[r];
#pragma unroll
            for (int m = 1; m < 16; m <<= 1) {
                vs += __shfl_xor(vs, m, 64);
                vd += __shfl_xor(vd, m, 64);
            }
            int gm = m0 + q * 4 + r;
            if (cl == 0 && gm < N) {
                a_src[gm * 4 + hh] = vs;
                a_dst[gm * 4 + hh] = vd;
            }
        }
    }
}

// ---------------- per-node aggregation (round-4 exact form, 66 us measured) ----------------
// Wave per node, lane = head*16 + ch16, depth-2 rotate pipeline on bucketed CSR.
__global__ __launch_bounds__(256) void k_agg(const unsigned short* __restrict__ hb,
                                             const float* __restrict__ a_src,
                                             const float* __restrict__ a_dst,
                                             const int* __restrict__ cnt,
                                             const int* __restrict__ csrB,
                                             const void* __restrict__ bias,
                                             unsigned short* __restrict__ outn,
                                             const int* __restrict__ flag) {
    int isbf = *flag;
    int wave = threadIdx.x >> 6, lane = threadIdx.x & 63;
    int n = blockIdx.x * 4 + wave;
    if (n >= N) return;
    int head = lane >> 4;
    float adn = a_dst[n * 4 + head];
    float wself = __expf(lrelu_att(a_src[n * 4 + head] + adn));
    ushort4 hv = *(const ushort4*)&hb[(size_t)n * HC + lane * 4];
    float4 acc;
    acc.x = us2f(hv.x) * wself;
    acc.y = us2f(hv.y) * wself;
    acc.z = us2f(hv.z) * wself;
    acc.w = us2f(hv.w) * wself;
    float ssum = wself;
    int dg = cnt[n]; if (dg > DCAP) dg = DCAP;
    const int* lst = csrB + (size_t)n * DCAP;
    int p0 = 0, p1 = dg;
    int p = p0;
    // pipeline state: group A = data in flight / being consumed; ib* = next group's indices
    ushort4 ga0, ga1, ga2, ga3;
    float wa0, wa1, wa2, wa3;
    int ib0 = 0, ib1 = 0, ib2 = 0, ib3 = 0;
    if (p + 4 <= p1) {
        int i0 = lst[p], i1 = lst[p + 1], i2 = lst[p + 2], i3 = lst[p + 3];
        ga0 = *(const ushort4*)&hb[(size_t)i0 * HC + lane * 4];
        ga1 = *(const ushort4*)&hb[(size_t)i1 * HC + lane * 4];
        ga2 = *(const ushort4*)&hb[(size_t)i2 * HC + lane * 4];
        ga3 = *(const ushort4*)&hb[(size_t)i3 * HC + lane * 4];
        wa0 = a_src[(size_t)i0 * 4 + head];
        wa1 = a_src[(size_t)i1 * 4 + head];
        wa2 = a_src[(size_t)i2 * 4 + head];
        wa3 = a_src[(size_t)i3 * 4 + head];
    }
    if (p + 8 <= p1) {
        ib0 = lst[p + 4]; ib1 = lst[p + 5]; ib2 = lst[p + 6]; ib3 = lst[p + 7];
    }
    while (p + 8 <= p1) {
        // issue group-B gathers immediately (indices already resident)
        ushort4 gb0 = *(const ushort4*)&hb[(size_t)ib0 * HC + lane * 4];
        ushort4 gb1 = *(const ushort4*)&hb[(size_t)ib1 * HC + lane * 4];
        ushort4 gb2 = *(const ushort4*)&hb[(size_t)ib2 * HC + lane * 4];
        ushort4 gb3 = *(const ushort4*)&hb[(size_t)ib3 * HC + lane * 4];
        float wb0 = a_src[(size_t)ib0 * 4 + head];
        float wb1 = a_src[(size_t)ib1 * 4 + head];
        float wb2 = a_src[(size_t)ib2 * 4 + head];
        float wb3 = a_src[(size_t)ib3 * 4 + head];
        // prefetch indices two groups ahead
        int ic0 = ib0, ic1 = ib1, ic2 = ib2, ic3 = ib3;
        if (p + 12 <= p1) {
            ic0 = lst[p + 8]; ic1 = lst[p + 9]; ic2 = lst[p + 10]; ic3 = lst[p + 11];
        }
        // consume group A (its loads have had a full iteration of latency cover)
        float e0 = __expf(lrelu_att(wa0 + adn));
        float e1 = __expf(lrelu_att(wa1 + adn));
        float e2 = __expf(lrelu_att(wa2 + adn));
        float e3 = __expf(lrelu_att(wa3 + adn));
        acc.x += us2f(ga0.x) * e0 + us2f(ga1.x) * e1 + us2f(ga2.x) * e2 + us2f(ga3.x) * e3;
        acc.y += us2f(ga0.y) * e0 + us2f(ga1.y) * e1 + us2f(ga2.y) * e2 + us2f(ga3.y) * e3;
        acc.z += us2f(ga0.z) * e0 + us2f(ga1.z) * e1 + us2f(ga2.z) * e2 + us2f(ga3.z) * e3;
        acc.w += us2f(ga0.w) * e0 + us2f(ga1.w) * e1 + us2f(ga2.w) * e2 + us2f(ga3.w) * e3;
        ssum += (e0 + e1) + (e2 + e3);
        // rotate B -> A
        ga0 = gb0; ga1 = gb1; ga2 = gb2; ga3 = gb3;
        wa0 = wb0; wa1 = wb1; wa2 = wb2; wa3 = wb3;
        ib0 = ic0; ib1 = ic1; ib2 = ic2; ib3 = ic3;
        p += 4;
    }
    if (p + 4 <= p1) {
        float e0 = __expf(lrelu_att(wa0 + adn));
        float e1 = __expf(lrelu_att(wa1 + adn));
        float e2 = __expf(lrelu_att(wa2 + adn));
        float e3 = __expf(lrelu_att(wa3 + adn));
        acc.x += us2f(ga0.x) * e0 + us2f(ga1.x) * e1 + us2f(ga2.x) * e2 + us2f(ga3.x) * e3;
        acc.y += us2f(ga0.y) * e0 + us2f(ga1.y) * e1 + us2f(ga2.y) * e2 + us2f(ga3.y) * e3;
        acc.z += us2f(ga0.z) * e0 + us2f(ga1.z) * e1 + us2f(ga2.z) * e2 + us2f(ga3.z) * e3;
        acc.w += us2f(ga0.w) * e0 + us2f(ga1.w) * e1 + us2f(ga2.w) * e2 + us2f(ga3.w) * e3;
        ssum += (e0 + e1) + (e2 + e3);
        p += 4;
    }
    for (; p < p1; p++) {
        int s = lst[p];
        float wv = __expf(lrelu_att(a_src[(size_t)s * 4 + head] + adn));
        ushort4 hs = *(const ushort4*)&hb[(size_t)s * HC + lane * 4];
        acc.x += us2f(hs.x) * wv;
        acc.y += us2f(hs.y) * wv;
        acc.z += us2f(hs.z) * wv;
        acc.w += us2f(hs.w) * wv;
        ssum += wv;
    }
    float inv = 1.f / ssum;
    ushort4 o;
    o.x = f2us(lrelu_act(acc.x * inv + ldin(bias, isbf, lane * 4 + 0)));
    o.y = f2us(lrelu_act(acc.y * inv + ldin(bias, isbf, lane * 4 + 1)));
    o.z = f2us(lrelu_act(acc.z * inv + ldin(bias, isbf, lane * 4 + 2)));
    o.w = f2us(lrelu_act(acc.w * inv + ldin(bias, isbf, lane * 4 + 3)));
    *(ushort4*)&outn[(size_t)n * HC + lane * 4] = o;
}

// ---------------- fused pool + FC: one 1024-thread block per graph ----------------
// Pooling quarter-split across the 4 wave-groups (pl4[4][256] in LDS), reduced,
// then FC with one output per thread (768 of 1024 active; fw reads coalesced).
// 4x the pooling parallelism of the round-9 256-thread version.
__global__ __launch_bounds__(1024) void k_fcp(const unsigned short* __restrict__ outn,
                                              const int* __restrict__ gs,
                                              const void* __restrict__ fw,
                                              const void* __restrict__ fb,
                                              void* __restrict__ out,
                                              const int* __restrict__ flag) {
    __shared__ float pl4[4][HC];
    __shared__ float pl[HC];
    int isbf = *flag;
    int g = blockIdx.x, t = threadIdx.x;
    int qq = t >> 8, ch = t & 255;
    int s = gs[g], e2 = gs[g + 1];
    int len = e2 - s;
    int r0 = s + (len * qq) / 4;
    int r1 = s + (len * (qq + 1)) / 4;
    float a0 = 0.f, a1 = 0.f, a2 = 0.f, a3 = 0.f;
    int r = r0;
    for (; r + 4 <= r1; r += 4) {
        a0 += us2f(outn[(size_t)(r + 0) * HC + ch]);
        a1 += us2f(outn[(size_t)(r + 1) * HC + ch]);
        a2 += us2f(outn[(size_t)(r + 2) * HC + ch]);
        a3 += us2f(outn[(size_t)(r + 3) * HC + ch]);
    }
    for (; r < r1; r++) a0 += us2f(outn[(size_t)r * HC + ch]);
    pl4[qq][ch] = (a0 + a1) + (a2 + a3);
    __syncthreads();
    if (t < HC) {
        float inv = 1.f / (float)(len > 1 ? len : 1);
        pl[t] = (pl4[0][t] + pl4[1][t] + pl4[2][t] + pl4[3][t]) * inv;
    }
    __syncthreads();
    if (t < NOUT) {
        float acc = ldin(fb, isbf, t);
#pragma unroll 8
        for (int k = 0; k < HC; k++) acc += pl[k] * ldin(fw, isbf, (size_t)k * NOUT + t);
        size_t oi = (size_t)g * NOUT + t;
        if (isbf) ((bf16*)out)[oi] = __float2bfloat16(acc);
        else      ((float*)out)[oi] = acc;
    }
}

extern "C" void kernel_launch(void* const* d_in, const int* in_sizes, int n_in,
                              void* d_out, int out_size, void* d_ws, size_t ws_size,
                              hipStream_t stream) {
    const void* x     = d_in[0];
    const int*  ei    = (const int*)d_in[1];
    const int*  batch = (const int*)d_in[2];
    const void* lin_w = d_in[3];
    const void* att_s = d_in[4];
    const void* att_d = d_in[5];
    const void* bias  = d_in[6];
    const void* fc1w  = d_in[7];
    const void* fc1b  = d_in[8];

    char* p = (char*)d_ws;
    unsigned short* hb   = (unsigned short*)p; p += (size_t)N * HC * 2;   // 25.6 MB
    unsigned short* outn = (unsigned short*)p; p += (size_t)N * HC * 2;   // 25.6 MB
    float* a_src  = (float*)p; p += (size_t)N * H * 4;
    float* a_dst  = (float*)p; p += (size_t)N * H * 4;
    int* cnt      = (int*)p;   p += (size_t)N * 4;
    int* csrB     = (int*)p;   p += (size_t)N * DCAP * 4;                 // 12.8 MB bucketed CSR
    unsigned short* bswz = (unsigned short*)p; p += (size_t)160 * 64 * 8 * 2;
    int* gs       = (int*)p;   p += (size_t)(G + 4) * 4;
    int* flag     = (int*)p;   p += 16;

    hipMemsetAsync(cnt, 0, (size_t)N * 4, stream);
    k_pre<<<41 + SCB, 256, 0, stream>>>((const unsigned short*)x, lin_w, batch,
                                        flag, bswz, gs, ei, cnt, csrB);
    k_lin4<<<1024, 256, 0, stream>>>(x, bswz, att_s, att_d, hb, a_src, a_dst, flag);
    k_agg<<<(N + 3) / 4, 256, 0, stream>>>(hb, a_src, a_dst, cnt, csrB, bias, outn, flag);
    k_fcp<<<G, 1024, 0, stream>>>(outn, gs, fc1w, fc1b, d_out, flag);
}